// Round 11
// baseline (341.138 us; speedup 1.0000x reference)
//
#include <hip/hip_runtime.h>
#include <math.h>

#define BN_EPS 1e-5f

constexpr int B  = 4;
constexpr int C  = 256;
constexpr int HW = 4096;   // 64*64
constexpr int CK = 64;
constexpr int CV = 256;
constexpr int CO = 320;    // CK + CV
constexpr int CHG = 2;     // fallback path
constexpr int JS  = 4;     // fallback path

typedef short bf16x8 __attribute__((ext_vector_type(8)));
typedef float f32x4  __attribute__((ext_vector_type(4)));

__device__ __forceinline__ ushort f2bf(float f) {
    unsigned u = __float_as_uint(f);
    u += 0x7FFFu + ((u >> 16) & 1u);      // round to nearest even
    return (ushort)(u >> 16);
}

// ---------------------------------------------------------------------------
// Kernel 0: fold BN into Wk (row-scale), emit bf16 weight table; zero Mx.
// ---------------------------------------------------------------------------
__global__ __launch_bounds__(256) void wprep(
    const float* __restrict__ Wk, const float* __restrict__ bk,
    const float* __restrict__ gamma, const float* __restrict__ beta,
    const float* __restrict__ mean,  const float* __restrict__ var,
    const float* __restrict__ Wv, const float* __restrict__ bv,
    ushort* __restrict__ Wq, float* __restrict__ bq, unsigned* __restrict__ Mx)
{
    const int co = blockIdx.x;
    const int c  = threadIdx.x;
    if (co == 0 && c < B) Mx[c] = 0u;
    float w;
    if (co < CK) {
        float inv = gamma[co] * rsqrtf(var[co] + BN_EPS);
        w = Wk[co * C + c] * inv;
        if (c == 0) bq[co] = bk[co] * inv + (beta[co] - mean[co] * inv);
    } else {
        w = Wv[(co - CK) * C + c];
        if (c == 0) bq[co] = bv[co - CK];
    }
    Wq[co * C + c] = f2bf(w);
}

// ---------------------------------------------------------------------------
// Kernel 1: KV projection as MFMA GEMM + fused K-norms (Cauchy-Schwarz bound).
// K -> Kbuf[b][hw][ck] bf16, V -> Vbuf[b][cv][hw] bf16.
// ---------------------------------------------------------------------------
__global__ __launch_bounds__(256) void kv_gemm(
    const float* __restrict__ x, const ushort* __restrict__ Wq,
    const float* __restrict__ bq,
    ushort* __restrict__ Kbuf, ushort* __restrict__ Vbuf,
    float* __restrict__ mb, unsigned* __restrict__ Mx)
{
    __shared__ __align__(16) ushort xt[16][C + 24];

    const int t    = threadIdx.x;
    const int lane = t & 63;
    const int wv   = t >> 6;
    const int q    = lane >> 4;
    const int col  = lane & 15;
    const int hw0  = blockIdx.x * 16;
    const int b    = blockIdx.y;

    const float* xb = x + (size_t)b * C * HW;

    {
        const int cq  = (t >> 4) * 4;
        const int hwo = t & 15;
#pragma unroll
        for (int pass = 0; pass < 4; pass++) {
            const int c0 = pass * 64 + cq;
            float a0 = xb[(size_t)(c0 + 0) * HW + hw0 + hwo];
            float a1 = xb[(size_t)(c0 + 1) * HW + hw0 + hwo];
            float a2 = xb[(size_t)(c0 + 2) * HW + hw0 + hwo];
            float a3 = xb[(size_t)(c0 + 3) * HW + hw0 + hwo];
            *(ushort4*)&xt[hwo][c0] = make_ushort4(f2bf(a0), f2bf(a1), f2bf(a2), f2bf(a3));
        }
    }
    __syncthreads();

    f32x4 acc[5];
#pragma unroll
    for (int mi = 0; mi < 5; mi++) acc[mi] = (f32x4){0.f, 0.f, 0.f, 0.f};

#pragma unroll
    for (int ks = 0; ks < 8; ks++) {
        bf16x8 av[5], bv1;
#pragma unroll
        for (int mi = 0; mi < 5; mi++)
            av[mi] = *(const bf16x8*)(Wq + (size_t)(wv * 80 + mi * 16 + col) * C + ks * 32 + q * 8);
        bv1 = *(const bf16x8*)&xt[col][ks * 32 + q * 8];
#pragma unroll
        for (int mi = 0; mi < 5; mi++)
            acc[mi] = __builtin_amdgcn_mfma_f32_16x16x32_bf16(av[mi], bv1, acc[mi], 0, 0, 0);
    }

    float ssq = 0.f;
#pragma unroll
    for (int mi = 0; mi < 5; mi++) {
        const int cot = wv * 80 + mi * 16;
        float bi[4];
#pragma unroll
        for (int r = 0; r < 4; r++) bi[r] = bq[cot + q * 4 + r];
        const int hw = hw0 + col;
        float v0 = acc[mi][0] + bi[0];
        float v1 = acc[mi][1] + bi[1];
        float v2 = acc[mi][2] + bi[2];
        float v3 = acc[mi][3] + bi[3];
        if (cot < CK) {
            ushort4 kk = make_ushort4(f2bf(v0), f2bf(v1), f2bf(v2), f2bf(v3));
            *(ushort4*)&Kbuf[((size_t)b * HW + hw) * CK + cot + q * 4] = kk;
            ssq += v0 * v0 + v1 * v1 + v2 * v2 + v3 * v3;
        } else {
            const int cv = cot - CK + q * 4;
            Vbuf[((size_t)b * CV + cv + 0) * HW + hw] = f2bf(v0);
            Vbuf[((size_t)b * CV + cv + 1) * HW + hw] = f2bf(v1);
            Vbuf[((size_t)b * CV + cv + 2) * HW + hw] = f2bf(v2);
            Vbuf[((size_t)b * CV + cv + 3) * HW + hw] = f2bf(v3);
        }
    }

    if (wv == 0) {
        float ss = ssq;
        ss += __shfl_xor(ss, 16, 64);
        ss += __shfl_xor(ss, 32, 64);
        float nr = sqrtf(ss);
        if (lane < 16) mb[(size_t)b * HW + hw0 + col] = nr;
        float mxn = nr;
#pragma unroll
        for (int off = 1; off <= 8; off <<= 1)
            mxn = fmaxf(mxn, __shfl_xor(mxn, off, 64));
        if (t == 0) atomicMax(Mx + b, __float_as_uint(mxn));
    }
}

// ---------------------------------------------------------------------------
// Kernel 2a: S = K_i.K_j GEMM + exp + bf16 P materialization + l atomics.
// Block: 128i x 128j tile; 4 waves in 2x2; frags direct from L2 (Kbuf 512KB/b).
// P[b][i][j] bf16 via per-wave LDS transpose -> coalesced b128 stores.
// l[b][i] += row-sums via atomicAdd (Lbuf pre-zeroed).
// ---------------------------------------------------------------------------
__global__ __launch_bounds__(256) void s_exp(
    const ushort* __restrict__ Kbuf, const float* __restrict__ mb,
    const unsigned* __restrict__ Mx, ushort* __restrict__ Pmat,
    float* __restrict__ Lbuf)
{
    __shared__ __align__(16) ushort Pl[4][64 * 72];   // per-wave 64x64 (+pad)
    __shared__ float mrowS[128];

    const int t    = threadIdx.x;
    const int lane = t & 63;
    const int wv   = t >> 6;
    const int q    = lane >> 4;
    const int col  = lane & 15;

    const int id = blockIdx.x;            // 4096 blocks
    const int b  = id >> 10;
    const int r2 = id & 1023;
    const int ix = r2 & 31, jy = r2 >> 5;
    const int i0 = ix * 128, j0 = jy * 128;
    const int wr = wv >> 1, wc = wv & 1;
    const int ib = i0 + wr * 64, jb = j0 + wc * 64;

    const ushort* Kb = Kbuf + (size_t)b * HW * CK;

    if (t < 128) mrowS[t] = mb[(size_t)b * HW + i0 + t] * __uint_as_float(Mx[b]);
    __syncthreads();

    bf16x8 a[4][2], bf[4][2];
#pragma unroll
    for (int mt = 0; mt < 4; mt++)
#pragma unroll
        for (int kk = 0; kk < 2; kk++)
            a[mt][kk] = *(const bf16x8*)(Kb + (size_t)(ib + mt * 16 + col) * CK + kk * 32 + q * 8);
#pragma unroll
    for (int nt = 0; nt < 4; nt++)
#pragma unroll
        for (int kk = 0; kk < 2; kk++)
            bf[nt][kk] = *(const bf16x8*)(Kb + (size_t)(jb + nt * 16 + col) * CK + kk * 32 + q * 8);

    f32x4 acc[4][4];
#pragma unroll
    for (int mt = 0; mt < 4; mt++)
#pragma unroll
        for (int nt = 0; nt < 4; nt++)
            acc[mt][nt] = (f32x4){0.f, 0.f, 0.f, 0.f};

#pragma unroll
    for (int mt = 0; mt < 4; mt++)
#pragma unroll
        for (int nt = 0; nt < 4; nt++) {
            acc[mt][nt] = __builtin_amdgcn_mfma_f32_16x16x32_bf16(a[mt][0], bf[nt][0], acc[mt][nt], 0, 0, 0);
            acc[mt][nt] = __builtin_amdgcn_mfma_f32_16x16x32_bf16(a[mt][1], bf[nt][1], acc[mt][nt], 0, 0, 0);
        }

    ushort* slab = &Pl[wv][0];
#pragma unroll
    for (int mt = 0; mt < 4; mt++) {
        float4 m4 = *(const float4*)&mrowS[wr * 64 + mt * 16 + q * 4];
        float rs0 = 0.f, rs1 = 0.f, rs2 = 0.f, rs3 = 0.f;
#pragma unroll
        for (int nt = 0; nt < 4; nt++) {
            float p0 = __expf(acc[mt][nt][0] - m4.x);
            float p1 = __expf(acc[mt][nt][1] - m4.y);
            float p2 = __expf(acc[mt][nt][2] - m4.z);
            float p3 = __expf(acc[mt][nt][3] - m4.w);
            rs0 += p0; rs1 += p1; rs2 += p2; rs3 += p3;
            slab[(mt * 16 + q * 4 + 0) * 72 + nt * 16 + col] = f2bf(p0);
            slab[(mt * 16 + q * 4 + 1) * 72 + nt * 16 + col] = f2bf(p1);
            slab[(mt * 16 + q * 4 + 2) * 72 + nt * 16 + col] = f2bf(p2);
            slab[(mt * 16 + q * 4 + 3) * 72 + nt * 16 + col] = f2bf(p3);
        }
        float rs[4] = {rs0, rs1, rs2, rs3};
#pragma unroll
        for (int r = 0; r < 4; r++) {
            float v = rs[r];
#pragma unroll
            for (int off = 1; off <= 8; off <<= 1)
                v += __shfl_xor(v, off, 64);
            if (col == 0)
                atomicAdd(Lbuf + (size_t)b * HW + ib + mt * 16 + q * 4 + r, v);
        }
    }

    // wave-private transpose readback -> coalesced global stores (no barrier)
#pragma unroll
    for (int pass = 0; pass < 8; pass++) {
        const int row = pass * 8 + (lane >> 3);
        const int jc  = (lane & 7) * 8;
        bf16x8 v = *(const bf16x8*)&slab[row * 72 + jc];
        *(bf16x8*)(Pmat + ((size_t)(b * HW + ib + row)) * HW + jb + jc) = v;
    }
}

// ---------------------------------------------------------------------------
// Kernel 2b: PV GEMM.  out[b][c][i] = (1/l_i) sum_j V[c][j] P[i][j]
// C[m=i][n=c]: A = P rows (j-contig), B = Vbuf rows (j-contig) — both direct.
// Block: 32 i x 256 c, K-loop over all 4096 j, register double-buffered.
// NO LDS, NO barriers — pure streaming GEMM (waves free-run).
// 512 blocks, XCD-swizzled: xcd pair owns batch b -> V L2-resident.
// ---------------------------------------------------------------------------
__global__ __launch_bounds__(256, 2) void pv_gemm(
    const ushort* __restrict__ Pmat, const ushort* __restrict__ Vbuf,
    const float* __restrict__ Lbuf, float* __restrict__ out)
{
    const int t    = threadIdx.x;
    const int lane = t & 63;
    const int wv   = t >> 6;
    const int q    = lane >> 4;
    const int col  = lane & 15;

    const int id   = blockIdx.x;          // 512
    const int xcd  = id & 7;
    const int b    = xcd >> 1;
    const int half = xcd & 1;
    const int slot = id >> 3;             // 0..63
    const int i0   = (half * 64 + slot) * 32;
    const int cb   = wv * 64;

    const ushort* Pb = Pmat + ((size_t)b * HW) * HW;
    const ushort* Vb = Vbuf + (size_t)b * CV * HW;

    f32x4 acc[2][4];
#pragma unroll
    for (int mt = 0; mt < 2; mt++)
#pragma unroll
        for (int nt = 0; nt < 4; nt++)
            acc[mt][nt] = (f32x4){0.f, 0.f, 0.f, 0.f};

    bf16x8 pa0[2][2], pa1[2][2], vb0[4][2], vb1[4][2];

#define LOAD_PA(DST, J)                                                        \
    _Pragma("unroll")                                                          \
    for (int mt = 0; mt < 2; mt++)                                             \
        _Pragma("unroll")                                                      \
        for (int kk = 0; kk < 2; kk++)                                         \
            DST[mt][kk] = *(const bf16x8*)(Pb + (size_t)(i0 + mt * 16 + col) * HW + (J) + kk * 32 + q * 8);
#define LOAD_VB(DST, J)                                                        \
    _Pragma("unroll")                                                          \
    for (int nt = 0; nt < 4; nt++)                                             \
        _Pragma("unroll")                                                      \
        for (int kk = 0; kk < 2; kk++)                                         \
            DST[nt][kk] = *(const bf16x8*)(Vb + (size_t)(cb + nt * 16 + col) * HW + (J) + kk * 32 + q * 8);
#define DO_MFMA(PA, VBW)                                                       \
    _Pragma("unroll")                                                          \
    for (int mt = 0; mt < 2; mt++)                                             \
        _Pragma("unroll")                                                      \
        for (int nt = 0; nt < 4; nt++) {                                       \
            acc[mt][nt] = __builtin_amdgcn_mfma_f32_16x16x32_bf16(PA[mt][0], VBW[nt][0], acc[mt][nt], 0, 0, 0); \
            acc[mt][nt] = __builtin_amdgcn_mfma_f32_16x16x32_bf16(PA[mt][1], VBW[nt][1], acc[mt][nt], 0, 0, 0); \
        }

    LOAD_PA(pa0, 0)
    LOAD_VB(vb0, 0)

    for (int j = 0; j < HW; j += 128) {
        const int j1 = j + 64;
        const int j2 = (j + 128) & (HW - 1);
        LOAD_PA(pa1, j1)
        LOAD_VB(vb1, j1)
        DO_MFMA(pa0, vb0)
        LOAD_PA(pa0, j2)
        LOAD_VB(vb0, j2)
        DO_MFMA(pa1, vb1)
    }

    float4 linv[2];
#pragma unroll
    for (int mt = 0; mt < 2; mt++) {
        float4 l4 = *(const float4*)(Lbuf + (size_t)b * HW + i0 + mt * 16 + q * 4);
        linv[mt].x = 1.f / l4.x; linv[mt].y = 1.f / l4.y;
        linv[mt].z = 1.f / l4.z; linv[mt].w = 1.f / l4.w;
    }

#pragma unroll
    for (int mt = 0; mt < 2; mt++)
#pragma unroll
        for (int nt = 0; nt < 4; nt++) {
            float4 o;
            o.x = acc[mt][nt][0] * linv[mt].x;
            o.y = acc[mt][nt][1] * linv[mt].y;
            o.z = acc[mt][nt][2] * linv[mt].z;
            o.w = acc[mt][nt][3] * linv[mt].w;
            *(float4*)(out + (size_t)(b * CV + cb + nt * 16 + col) * HW + i0 + mt * 16 + q * 4) = o;
        }
}

// ---------------------------------------------------------------------------
// FALLBACK (ws too small for Pmat): R9's proven flash attention + norm_out.
// ---------------------------------------------------------------------------
#define ATTN_TILE_FB(KC, KN, J0, JN)                                           \
    {                                                                          \
        const int j0_ = (J0), jn_ = (JN);                                      \
        bf16x8 vf[2][2];                                                       \
        _Pragma("unroll")                                                      \
        for (int mt = 0; mt < 2; mt++)                                         \
            _Pragma("unroll")                                                  \
            for (int k = 0; k < 2; k++)                                        \
                vf[mt][k] = *(const bf16x8*)(Vb + (size_t)(cbase + mt * 16 + col) * HW + j0_ + k * 32 + q * 8); \
        f32x4 S[4];                                                            \
        _Pragma("unroll")                                                      \
        for (int nt = 0; nt < 4; nt++) {                                       \
            S[nt] = __builtin_amdgcn_mfma_f32_16x16x32_bf16(qa[0], KC[nt][0], zf, 0, 0, 0); \
            S[nt] = __builtin_amdgcn_mfma_f32_16x16x32_bf16(qa[1], KC[nt][1], S[nt], 0, 0, 0); \
        }                                                                      \
        float p[4][4];                                                         \
        _Pragma("unroll")                                                      \
        for (int nt = 0; nt < 4; nt++)                                         \
            _Pragma("unroll")                                                  \
            for (int r = 0; r < 4; r++)                                        \
                p[nt][r] = __expf(S[nt][r] - m_i[r]);                          \
        _Pragma("unroll")                                                      \
        for (int r = 0; r < 4; r++)                                            \
            l_r[r] += (p[0][r] + p[1][r]) + (p[2][r] + p[3][r]);               \
        __syncthreads();                                                       \
        _Pragma("unroll")                                                      \
        for (int nt = 0; nt < 4; nt++)                                         \
            _Pragma("unroll")                                                  \
            for (int r = 0; r < 4; r++)                                        \
                Ps[wv * 16 + q * 4 + r][nt * 16 + col] = f2bf(p[nt][r]);       \
        __syncthreads();                                                       \
        _Pragma("unroll")                                                      \
        for (int nt = 0; nt < 4; nt++)                                         \
            _Pragma("unroll")                                                  \
            for (int k = 0; k < 2; k++)                                        \
                KN[nt][k] = *(const bf16x8*)(Kb + (size_t)(jn_ + nt * 16 + col) * CK + k * 32 + q * 8); \
        bf16x8 pf[4][2];                                                       \
        _Pragma("unroll")                                                      \
        for (int nt = 0; nt < 4; nt++)                                         \
            _Pragma("unroll")                                                  \
            for (int k = 0; k < 2; k++)                                        \
                pf[nt][k] = *(const bf16x8*)&Ps[nt * 16 + col][k * 32 + q * 8]; \
        _Pragma("unroll")                                                      \
        for (int mt = 0; mt < 2; mt++)                                         \
            _Pragma("unroll")                                                  \
            for (int nt = 0; nt < 4; nt++) {                                   \
                Oacc[mt][nt] = __builtin_amdgcn_mfma_f32_16x16x32_bf16(vf[mt][0], pf[nt][0], Oacc[mt][nt], 0, 0, 0); \
                Oacc[mt][nt] = __builtin_amdgcn_mfma_f32_16x16x32_bf16(vf[mt][1], pf[nt][1], Oacc[mt][nt], 0, 0, 0); \
            }                                                                  \
    }

__global__ __launch_bounds__(256, 2) void attn_fb(
    const ushort* __restrict__ Kbuf, const ushort* __restrict__ Vbuf,
    const float* __restrict__ mb, const unsigned* __restrict__ Mx,
    float* __restrict__ out, float* __restrict__ Lbuf)
{
    __shared__ __align__(16) ushort Ps[64][72];

    const int t    = threadIdx.x;
    const int lane = t & 63;
    const int wv   = t >> 6;
    const int q    = lane >> 4;
    const int col  = lane & 15;

    const int id    = blockIdx.x;
    const int xcd   = id & 7;
    const int slot  = id >> 3;
    const int combo = (xcd << 1) | (slot >> 7);
    const int b     = combo >> 2;
    const int js    = combo & 3;
    const int rem   = slot & 127;
    const int chg   = rem & 1;
    const int i0g   = (rem >> 1) * 64;
    const int jbase = js * (HW / JS);

    const ushort* Kb = Kbuf + (size_t)b * HW * CK;
    const ushort* Vb = Vbuf + (size_t)b * CV * HW;

    bf16x8 qa[2];
#pragma unroll
    for (int k = 0; k < 2; k++)
        qa[k] = *(const bf16x8*)(Kb + (size_t)(i0g + wv * 16 + col) * CK + k * 32 + q * 8);

    const float Mxf = __uint_as_float(Mx[b]);
    float m_i[4];
#pragma unroll
    for (int r = 0; r < 4; r++)
        m_i[r] = mb[(size_t)b * HW + i0g + wv * 16 + q * 4 + r] * Mxf;

    f32x4 Oacc[2][4];
#pragma unroll
    for (int mt = 0; mt < 2; mt++)
#pragma unroll
        for (int nt = 0; nt < 4; nt++)
            Oacc[mt][nt] = (f32x4){0.f, 0.f, 0.f, 0.f};

    float l_r[4] = {0.f, 0.f, 0.f, 0.f};
    const f32x4 zf = (f32x4){0.f, 0.f, 0.f, 0.f};
    const int cbase = chg * 128 + wv * 32;

    bf16x8 kf0[4][2], kf1[4][2];
#pragma unroll
    for (int nt = 0; nt < 4; nt++)
#pragma unroll
        for (int k = 0; k < 2; k++)
            kf0[nt][k] = *(const bf16x8*)(Kb + (size_t)(jbase + nt * 16 + col) * CK + k * 32 + q * 8);

    for (int j0 = jbase; j0 < jbase + HW / JS; j0 += 128) {
        ATTN_TILE_FB(kf0, kf1, j0,      j0 + 64);
        ATTN_TILE_FB(kf1, kf0, j0 + 64, (j0 + 128) & (HW - 1));
    }

#pragma unroll
    for (int r = 0; r < 4; r++) {
        float v = l_r[r];
#pragma unroll
        for (int off = 1; off <= 8; off <<= 1)
            v += __shfl_xor(v, off, 64);
        if (chg == 0 && col == 0)
            Lbuf[((size_t)b * JS + js) * HW + i0g + wv * 16 + q * 4 + r] = v;
    }

    float* ob = out + (size_t)b * CV * HW;
#pragma unroll
    for (int mt = 0; mt < 2; mt++)
#pragma unroll
        for (int r = 0; r < 4; r++) {
            size_t c = cbase + mt * 16 + q * 4 + r;
#pragma unroll
            for (int nt = 0; nt < 4; nt++)
                atomicAdd(&ob[c * HW + i0g + nt * 16 + col], Oacc[mt][nt][r]);
        }
}

__global__ __launch_bounds__(256) void norm_out(
    float* __restrict__ out, const float* __restrict__ Lbuf)
{
    const int g    = blockIdx.x * 256 + threadIdx.x;
    const int flat = g * 4;
    const int i    = flat & (HW - 1);
    const int b    = flat >> 20;
    float4 o = *(float4*)&out[flat];
    float lx = 0.f, ly = 0.f, lz = 0.f, lw = 0.f;
#pragma unroll
    for (int js = 0; js < JS; js++) {
        const float4 l4 = *(const float4*)&Lbuf[((size_t)b * JS + js) * HW + i];
        lx += l4.x; ly += l4.y; lz += l4.z; lw += l4.w;
    }
    o.x /= lx; o.y /= ly; o.z /= lz; o.w /= lw;
    *(float4*)&out[flat] = o;
}

// ---------------------------------------------------------------------------
extern "C" void kernel_launch(void* const* d_in, const int* in_sizes, int n_in,
                              void* d_out, int out_size, void* d_ws, size_t ws_size,
                              hipStream_t stream)
{
    const float* x     = (const float*)d_in[0];
    const float* Wk    = (const float*)d_in[1];
    const float* bk    = (const float*)d_in[2];
    const float* gamma = (const float*)d_in[3];
    const float* beta  = (const float*)d_in[4];
    const float* mean  = (const float*)d_in[5];
    const float* var   = (const float*)d_in[6];
    const float* Wv    = (const float*)d_in[7];
    const float* bv    = (const float*)d_in[8];
    float* out = (float*)d_out;

    ushort*   Kbuf = (ushort*)d_ws;                          // [B][HW][CK]  2 MB
    ushort*   Vbuf = Kbuf + (size_t)B * HW * CK;             // [B][CV][HW]  8.4 MB
    ushort*   Wq   = Vbuf + (size_t)B * CV * HW;             // [320][256]
    float*    bq   = (float*)(Wq + (size_t)CO * C);          // [320]
    float*    mb   = bq + CO;                                // [B][HW]
    float*    Lbuf = mb + (size_t)B * HW;                    // [B][JS][HW] / [B][HW]
    unsigned* Mx   = (unsigned*)(Lbuf + (size_t)B * JS * HW);// [B]
    ushort*   Pmat = (ushort*)(Mx + 16);                     // [B][HW][HW] bf16 134 MB

    const size_t need = ((char*)(Pmat + (size_t)B * HW * HW) - (char*)d_ws);

    wprep<<<dim3(CO), 256, 0, stream>>>(Wk, bk, gamma, beta, mean, var, Wv, bv, Wq, bq, Mx);
    kv_gemm<<<dim3(HW / 16, B), 256, 0, stream>>>(x, Wq, bq, Kbuf, Vbuf, mb, Mx);

    if (ws_size >= need) {
        // main path: materialized-P 3-GEMM pipeline
        hipMemsetAsync(Lbuf, 0, (size_t)B * HW * sizeof(float), stream);
        s_exp<<<dim3(4096), 256, 0, stream>>>(Kbuf, mb, Mx, Pmat, Lbuf);
        pv_gemm<<<dim3(512), 256, 0, stream>>>(Pmat, Vbuf, Lbuf, out);
    } else {
        // fallback: R9 flash path
        hipMemsetAsync(out, 0, (size_t)out_size * sizeof(float), stream);
        attn_fb<<<dim3(2048), 256, 0, stream>>>(Kbuf, Vbuf, mb, Mx, out, Lbuf);
        norm_out<<<dim3(out_size / 4 / 256), 256, 0, stream>>>(out, Lbuf);
    }
}